// Round 11
// baseline (270.629 us; speedup 1.0000x reference)
//
#include <hip/hip_runtime.h>

#define N_NODESC 100000
#define N_EDGESC 1600000
#define BN_EPSC 1e-5f
#define NBUCK 2048              // coarse buckets (dst>>6, 64 nodes each), 1563 used
#define NUSED 1563              // ceil(100000/64)
#define SBLK 256                // scatter/hist blocks
#define EPB (N_EDGESC / SBLK)   // 6250 edges per block
#define HN (NBUCK * SBLK)       // 524288 hist entries
#define MT 128                  // nodes per mlp2 block
#define BCAP 1536               // LDS edge cap per bucket (mean 1024, 16 sigma)

// ---------------------------------------------------------------------------
// K_hist_cast: coarse histogram (Hm bucket-major, 2 buckets/thread) +
// batched bf16 cast of x + zero cs/css (block 0).
// ---------------------------------------------------------------------------
__global__ __launch_bounds__(1024) void k_hist_cast(
    const int* __restrict__ ei, int* __restrict__ Hm,
    const float* __restrict__ x, uint2* __restrict__ xh4,
    float* __restrict__ cs0)
{
    __shared__ int h[NBUCK];
    const int t = threadIdx.x;
    const int k = blockIdx.x;
    h[t] = 0;
    h[t + 1024] = 0;
    __syncthreads();
    const int base = k * EPB;
    #pragma unroll
    for (int i = 0; i < 7; i++) {
        const int e = base + i * 1024 + t;
        if (e < base + EPB) atomicAdd(&h[ei[N_EDGESC + e] >> 6], 1);
    }
    {   // cast 1.6M float4 -> bf16x4 (RNE), batched for ILP
        const float4* x4 = (const float4*)x;
        const int g = k * 1024 + t;
        float4 v[7];
        bool m[7];
        #pragma unroll
        for (int i = 0; i < 7; i++) {
            const int idx = g + i * (SBLK * 1024);
            m[i] = (idx < N_NODESC * 16);
            if (m[i]) v[i] = x4[idx];
        }
        #pragma unroll
        for (int i = 0; i < 7; i++) {
            if (m[i]) {
                const int idx = g + i * (SBLK * 1024);
                unsigned int a = __float_as_uint(v[i].x);
                unsigned int b = __float_as_uint(v[i].y);
                unsigned int c = __float_as_uint(v[i].z);
                unsigned int d = __float_as_uint(v[i].w);
                a = (a + 0x7FFFu + ((a >> 16) & 1u)) >> 16;
                b = (b + 0x7FFFu + ((b >> 16) & 1u)) >> 16;
                c = (c + 0x7FFFu + ((c >> 16) & 1u)) >> 16;
                d = (d + 0x7FFFu + ((d >> 16) & 1u)) >> 16;
                xh4[idx] = make_uint2(a | (b << 16), c | (d << 16));
            }
        }
    }
    if (k == 0 && t < 128) cs0[t] = 0.f;   // zero cs+css (contiguous)
    __syncthreads();
    Hm[t * SBLK + k] = h[t];
    Hm[(t + 1024) * SBLK + k] = h[t + 1024];
}

// ---------------------------------------------------------------------------
// K_scan1: per-bucket exclusive scan of 256 counts + bucket totals.
// ---------------------------------------------------------------------------
__global__ __launch_bounds__(256) void k_scan1(
    const int* __restrict__ in, int* __restrict__ local, int* __restrict__ bsum)
{
    __shared__ int wsum[4];
    const int t = threadIdx.x;
    const int i = blockIdx.x * 256 + t;
    const int lane = t & 63;
    const int wid = t >> 6;
    const int v = in[i];
    int inc = v;
    #pragma unroll
    for (int d = 1; d < 64; d <<= 1) {
        const int u = __shfl_up(inc, d);
        if (lane >= d) inc += u;
    }
    if (lane == 63) wsum[wid] = inc;
    __syncthreads();
    int add = 0;
    #pragma unroll
    for (int w = 0; w < 3; w++) if (w < wid) add += wsum[w];
    local[i] = inc - v + add;
    if (t == 255) bsum[blockIdx.x] = add + inc;
}

// ---------------------------------------------------------------------------
// K_scatter2: edges -> coarse buckets; 2048-bucket prefix via pair-per-thread
// Hillis-Steele in LDS.  tmp = src(17b) | attr<<17(2b) | (dst&63)<<19(6b).
// ---------------------------------------------------------------------------
__global__ __launch_bounds__(1024) void k_scatter2(
    const int* __restrict__ ei, const int* __restrict__ ea,
    const int* __restrict__ Sloc, const int* __restrict__ bsum,
    int* __restrict__ tmp)
{
    __shared__ int s[1024];
    __shared__ int lcur[NBUCK];
    const int t = threadIdx.x;
    const int k = blockIdx.x;
    const int v0 = bsum[2 * t];
    const int v1 = bsum[2 * t + 1];
    const int p = v0 + v1;
    s[t] = p;
    __syncthreads();
    for (int d = 1; d < 1024; d <<= 1) {
        const int u = (t >= d) ? s[t - d] : 0;
        __syncthreads();
        s[t] += u;
        __syncthreads();
    }
    const int excl = s[t] - p;   // exclusive prefix of pair sums
    lcur[2 * t]     = Sloc[(2 * t) * SBLK + k] + excl;
    lcur[2 * t + 1] = Sloc[(2 * t + 1) * SBLK + k] + excl + v0;
    __syncthreads();
    const int base = k * EPB;
    #pragma unroll
    for (int i = 0; i < 7; i++) {
        const int e = base + i * 1024 + t;
        if (e < base + EPB) {
            const int src = ei[e];
            const int dst = ei[N_EDGESC + e];
            const int a = ea[e];
            const int pos = atomicAdd(&lcur[dst >> 6], 1);
            tmp[pos] = src | (a << 17) | ((dst & 63) << 19);
        }
    }
}

// ---------------------------------------------------------------------------
// K_aggmlp: one block per 64-node bucket.  Phase A: sort bucket edges into
// LDS (node-major).  Phase B: register aggregation with self-term init
// (1+eps)*x.  Phase C: 64x64 GEMM (W1 from global/L1) + bias + BN partial
// sums.  Writes h1 rows; eliminates the agg round-trip and mlp1 entirely.
// ---------------------------------------------------------------------------
__global__ __launch_bounds__(256) void k_aggmlp(
    const ushort* __restrict__ xh, const float* __restrict__ emb,
    const float* __restrict__ x,
    const float* __restrict__ W1, const float* __restrict__ b1,
    const float* __restrict__ epsp,
    const int* __restrict__ bsum, const int* __restrict__ tmp,
    float* __restrict__ h1, float* __restrict__ cs, float* __restrict__ css)
{
    __shared__ int packedL[BCAP];
    __shared__ float lin[64][68];
    __shared__ int cnt[64];
    __shared__ int cst[64];
    __shared__ int cur[64];
    __shared__ int red[4];
    __shared__ float redS[4][64];
    __shared__ float redQ[4][64];
    const int t = threadIdx.x;
    const int b = blockIdx.x;

    // ---- phase A: bucket start + per-node sort into LDS ----------------
    int part = 0;
    #pragma unroll
    for (int j = 0; j < 8; j++) {
        const int idx = t * 8 + j;
        const int bv = bsum[idx];
        if (idx < b) part += bv;
    }
    #pragma unroll
    for (int o = 1; o < 64; o <<= 1) part += __shfl_xor(part, o);
    if ((t & 63) == 0) red[t >> 6] = part;
    if (t < 64) cnt[t] = 0;
    __syncthreads();
    const int start = red[0] + red[1] + red[2] + red[3];
    const int cntb = bsum[b];

    for (int e = t; e < cntb; e += 256)
        atomicAdd(&cnt[(tmp[start + e] >> 19) & 63], 1);
    __syncthreads();
    if (t < 64) {
        const int v = cnt[t];
        int inc = v;
        #pragma unroll
        for (int d = 1; d < 64; d <<= 1) {
            const int u = __shfl_up(inc, d);
            if (t >= d) inc += u;
        }
        cst[t] = inc - v;
        cur[t] = inc - v;
    }
    __syncthreads();
    for (int e = t; e < cntb; e += 256) {
        const int p = tmp[start + e];
        const int pos = atomicAdd(&cur[(p >> 19) & 63], 1);
        if (pos < BCAP) packedL[pos] = p;
    }
    __syncthreads();

    // ---- phase B: aggregate 4 nodes/group, acc init = (1+eps)*x --------
    {
        const int g = t >> 4;
        const int q = t & 15;
        const float sc1 = 1.0f + epsp[0];
        const ushort4* xv4 = (const ushort4*)xh;
        const float4* x4 = (const float4*)x;
        const float4* e4 = (const float4*)emb;
        #pragma unroll
        for (int j = 0; j < 4; j++) {
            const int nl = g * 4 + j;
            const int n = b * 64 + nl;
            float4 acc = make_float4(0.f, 0.f, 0.f, 0.f);
            if (n < N_NODESC) {
                const float4 xv = x4[(size_t)n * 16 + q];
                acc.x = sc1 * xv.x; acc.y = sc1 * xv.y;
                acc.z = sc1 * xv.z; acc.w = sc1 * xv.w;
            }
            int e = cst[nl];
            const int ee = cur[nl];
            for (; e + 2 <= ee; e += 2) {
                const int p0 = packedL[e];
                const int p1 = packedL[e + 1];
                const ushort4 u0 = xv4[(size_t)(p0 & 0x1FFFF) * 16 + q];
                const ushort4 u1 = xv4[(size_t)(p1 & 0x1FFFF) * 16 + q];
                const float4 t0 = e4[((p0 >> 17) & 3) * 16 + q];
                const float4 t1 = e4[((p1 >> 17) & 3) * 16 + q];
                acc.x += fmaxf(__uint_as_float((unsigned int)u0.x << 16) + t0.x, 0.f)
                       + fmaxf(__uint_as_float((unsigned int)u1.x << 16) + t1.x, 0.f);
                acc.y += fmaxf(__uint_as_float((unsigned int)u0.y << 16) + t0.y, 0.f)
                       + fmaxf(__uint_as_float((unsigned int)u1.y << 16) + t1.y, 0.f);
                acc.z += fmaxf(__uint_as_float((unsigned int)u0.z << 16) + t0.z, 0.f)
                       + fmaxf(__uint_as_float((unsigned int)u1.z << 16) + t1.z, 0.f);
                acc.w += fmaxf(__uint_as_float((unsigned int)u0.w << 16) + t0.w, 0.f)
                       + fmaxf(__uint_as_float((unsigned int)u1.w << 16) + t1.w, 0.f);
            }
            if (e < ee) {
                const int p0 = packedL[e];
                const ushort4 u0 = xv4[(size_t)(p0 & 0x1FFFF) * 16 + q];
                const float4 t0 = e4[((p0 >> 17) & 3) * 16 + q];
                acc.x += fmaxf(__uint_as_float((unsigned int)u0.x << 16) + t0.x, 0.f);
                acc.y += fmaxf(__uint_as_float((unsigned int)u0.y << 16) + t0.y, 0.f);
                acc.z += fmaxf(__uint_as_float((unsigned int)u0.z << 16) + t0.z, 0.f);
                acc.w += fmaxf(__uint_as_float((unsigned int)u0.w << 16) + t0.w, 0.f);
            }
            *(float4*)&lin[nl][q * 4] = acc;
        }
    }
    __syncthreads();

    // ---- phase C: GEMM 64x64 + bias + BN partial sums ------------------
    const int g = t & 7;     // cols g*8..g*8+7
    const int r0 = t >> 3;   // nodes r0, r0+32
    const float4* W4 = (const float4*)W1;
    const float4* b4 = (const float4*)b1;
    const float4 bb0 = b4[g * 2 + 0];
    const float4 bb1 = b4[g * 2 + 1];
    float4 a00 = bb0, a01 = bb1, a10 = bb0, a11 = bb1;
    for (int k = 0; k < 64; k++) {
        const float v0 = lin[r0][k];
        const float v1 = lin[r0 + 32][k];
        const float4 w0 = W4[k * 16 + g * 2 + 0];
        const float4 w1 = W4[k * 16 + g * 2 + 1];
        a00.x = fmaf(v0, w0.x, a00.x); a00.y = fmaf(v0, w0.y, a00.y);
        a00.z = fmaf(v0, w0.z, a00.z); a00.w = fmaf(v0, w0.w, a00.w);
        a01.x = fmaf(v0, w1.x, a01.x); a01.y = fmaf(v0, w1.y, a01.y);
        a01.z = fmaf(v0, w1.z, a01.z); a01.w = fmaf(v0, w1.w, a01.w);
        a10.x = fmaf(v1, w0.x, a10.x); a10.y = fmaf(v1, w0.y, a10.y);
        a10.z = fmaf(v1, w0.z, a10.z); a10.w = fmaf(v1, w0.w, a10.w);
        a11.x = fmaf(v1, w1.x, a11.x); a11.y = fmaf(v1, w1.y, a11.y);
        a11.z = fmaf(v1, w1.z, a11.z); a11.w = fmaf(v1, w1.w, a11.w);
    }
    const int n0 = b * 64 + r0;
    const int n1 = n0 + 32;
    float4* h4 = (float4*)h1;
    const float m0 = (n0 < N_NODESC) ? 1.0f : 0.0f;
    const float m1 = (n1 < N_NODESC) ? 1.0f : 0.0f;
    if (n0 < N_NODESC) {
        h4[(size_t)n0 * 16 + g * 2 + 0] = a00;
        h4[(size_t)n0 * 16 + g * 2 + 1] = a01;
    }
    if (n1 < N_NODESC) {
        h4[(size_t)n1 * 16 + g * 2 + 0] = a10;
        h4[(size_t)n1 * 16 + g * 2 + 1] = a11;
    }

    float vs[8], vq[8];
    {
        const float e0[8] = {a00.x, a00.y, a00.z, a00.w, a01.x, a01.y, a01.z, a01.w};
        const float e1[8] = {a10.x, a10.y, a10.z, a10.w, a11.x, a11.y, a11.z, a11.w};
        #pragma unroll
        for (int c = 0; c < 8; c++) {
            const float u0 = e0[c] * m0;
            const float u1 = e1[c] * m1;
            vs[c] = u0 + u1;
            vq[c] = u0 * e0[c] + u1 * e1[c];
        }
    }
    #pragma unroll
    for (int o = 8; o < 64; o <<= 1) {
        #pragma unroll
        for (int c = 0; c < 8; c++) {
            vs[c] += __shfl_xor(vs[c], o);
            vq[c] += __shfl_xor(vq[c], o);
        }
    }
    const int lane = t & 63;
    const int w = t >> 6;
    if (lane < 8) {
        #pragma unroll
        for (int c = 0; c < 8; c++) {
            redS[w][lane * 8 + c] = vs[c];
            redQ[w][lane * 8 + c] = vq[c];
        }
    }
    __syncthreads();
    if (t < 64) {
        const float s = redS[0][t] + redS[1][t] + redS[2][t] + redS[3][t];
        const float qq = redQ[0][t] + redQ[1][t] + redQ[2][t] + redQ[3][t];
        unsafeAtomicAdd(&cs[t], s);
        unsafeAtomicAdd(&css[t], qq);
    }
}

// ---------------------------------------------------------------------------
// K_mlp2: out = relu(BN(h1)) @ W2 + b2.  h1 aliases out; LDS-staged.
// ---------------------------------------------------------------------------
__global__ __launch_bounds__(256) void k_mlp2(
    const float* h1, const float* __restrict__ W2, const float* __restrict__ b2,
    const float* __restrict__ gamma, const float* __restrict__ beta,
    const float* __restrict__ cs, const float* __restrict__ css,
    float* out)
{
    __shared__ float lin[MT][68];
    __shared__ float lW[4096];
    __shared__ float scl[64];
    __shared__ float sft[64];
    const int t = threadIdx.x;
    const int nbase = blockIdx.x * MT;

    if (t < 64) {
        const float inv = 1.0f / (float)N_NODESC;
        const float mu = cs[t] * inv;
        const float var = css[t] * inv - mu * mu;
        const float rs = rsqrtf(var + BN_EPSC);
        const float s = rs * gamma[t];
        scl[t] = s;
        sft[t] = fmaf(-mu, s, beta[t]);
    }
    {
        const float4* W4 = (const float4*)W2;
        float4* lW4 = (float4*)lW;
        #pragma unroll
        for (int i = 0; i < 4; i++) lW4[i * 256 + t] = W4[i * 256 + t];
    }
    __syncthreads();
    {
        const float4* h4 = (const float4*)h1;
        #pragma unroll
        for (int i = 0; i < 8; i++) {
            const int fidx = i * 256 + t;
            const int row = fidx >> 4;
            const int q = fidx & 15;
            const int n = nbase + row;
            float4 v = make_float4(0.f, 0.f, 0.f, 0.f);
            if (n < N_NODESC) {
                const float4 h = h4[(size_t)n * 16 + q];
                const int c = q * 4;
                v.x = fmaxf(fmaf(h.x, scl[c + 0], sft[c + 0]), 0.f);
                v.y = fmaxf(fmaf(h.y, scl[c + 1], sft[c + 1]), 0.f);
                v.z = fmaxf(fmaf(h.z, scl[c + 2], sft[c + 2]), 0.f);
                v.w = fmaxf(fmaf(h.w, scl[c + 3], sft[c + 3]), 0.f);
            }
            *(float4*)&lin[row][q * 4] = v;
        }
    }
    __syncthreads();

    const int g = t & 7;
    const int r0 = t >> 3;
    const float4* lW4 = (const float4*)lW;
    const float4* b4 = (const float4*)b2;
    const float4 bb0 = b4[g * 2 + 0];
    const float4 bb1 = b4[g * 2 + 1];
    float4 a00 = bb0, a01 = bb1, a10 = bb0, a11 = bb1;
    float4 a20 = bb0, a21 = bb1, a30 = bb0, a31 = bb1;
    for (int k = 0; k < 64; k++) {
        const float v0 = lin[r0][k];
        const float v1 = lin[r0 + 32][k];
        const float v2 = lin[r0 + 64][k];
        const float v3 = lin[r0 + 96][k];
        const float4 w0 = lW4[k * 16 + g * 2 + 0];
        const float4 w1 = lW4[k * 16 + g * 2 + 1];
        a00.x = fmaf(v0, w0.x, a00.x); a00.y = fmaf(v0, w0.y, a00.y);
        a00.z = fmaf(v0, w0.z, a00.z); a00.w = fmaf(v0, w0.w, a00.w);
        a01.x = fmaf(v0, w1.x, a01.x); a01.y = fmaf(v0, w1.y, a01.y);
        a01.z = fmaf(v0, w1.z, a01.z); a01.w = fmaf(v0, w1.w, a01.w);
        a10.x = fmaf(v1, w0.x, a10.x); a10.y = fmaf(v1, w0.y, a10.y);
        a10.z = fmaf(v1, w0.z, a10.z); a10.w = fmaf(v1, w0.w, a10.w);
        a11.x = fmaf(v1, w1.x, a11.x); a11.y = fmaf(v1, w1.y, a11.y);
        a11.z = fmaf(v1, w1.z, a11.z); a11.w = fmaf(v1, w1.w, a11.w);
        a20.x = fmaf(v2, w0.x, a20.x); a20.y = fmaf(v2, w0.y, a20.y);
        a20.z = fmaf(v2, w0.z, a20.z); a20.w = fmaf(v2, w0.w, a20.w);
        a21.x = fmaf(v2, w1.x, a21.x); a21.y = fmaf(v2, w1.y, a21.y);
        a21.z = fmaf(v2, w1.z, a21.z); a21.w = fmaf(v2, w1.w, a21.w);
        a30.x = fmaf(v3, w0.x, a30.x); a30.y = fmaf(v3, w0.y, a30.y);
        a30.z = fmaf(v3, w0.z, a30.z); a30.w = fmaf(v3, w0.w, a30.w);
        a31.x = fmaf(v3, w1.x, a31.x); a31.y = fmaf(v3, w1.y, a31.y);
        a31.z = fmaf(v3, w1.z, a31.z); a31.w = fmaf(v3, w1.w, a31.w);
    }
    const float4 A0[4] = {a00, a10, a20, a30};
    const float4 A1[4] = {a01, a11, a21, a31};
    float4* o4 = (float4*)out;
    #pragma unroll
    for (int j = 0; j < 4; j++) {
        const int n = nbase + r0 + 32 * j;
        if (n < N_NODESC) {
            o4[(size_t)n * 16 + g * 2 + 0] = A0[j];
            o4[(size_t)n * 16 + g * 2 + 1] = A1[j];
        }
    }
}

// ---------------------------------------------------------------------------
extern "C" void kernel_launch(void* const* d_in, const int* in_sizes, int n_in,
                              void* d_out, int out_size, void* d_ws, size_t ws_size,
                              hipStream_t stream) {
    const float* x     = (const float*)d_in[0];
    const float* emb   = (const float*)d_in[1];
    const float* eps   = (const float*)d_in[2];
    const float* W1    = (const float*)d_in[3];
    const float* b1    = (const float*)d_in[4];
    const float* gamma = (const float*)d_in[5];
    const float* beta  = (const float*)d_in[6];
    const float* W2    = (const float*)d_in[7];
    const float* b2    = (const float*)d_in[8];
    const int*   ei    = (const int*)d_in[9];
    const int*   ea    = (const int*)d_in[10];
    float* out = (float*)d_out;

    // ws: [cs 64][css 64][Hm HN][Sloc HN][bsum NBUCK][tmp E][xh N*64 bf16]
    float* ws    = (float*)d_ws;
    float* cs    = ws;
    float* css   = ws + 64;
    int*   Hm    = (int*)(ws + 128);
    int*   Sloc  = Hm + HN;
    int*   bsum  = Sloc + HN;
    int*   tmp   = bsum + NBUCK;
    ushort* xh   = (ushort*)(tmp + N_EDGESC);

    k_hist_cast<<<SBLK, 1024, 0, stream>>>(ei, Hm, x, (uint2*)xh, cs);
    k_scan1<<<HN / 256, 256, 0, stream>>>(Hm, Sloc, bsum);
    k_scatter2<<<SBLK, 1024, 0, stream>>>(ei, ea, Sloc, bsum, tmp);
    k_aggmlp<<<NUSED, 256, 0, stream>>>(xh, emb, x, W1, b1, eps, bsum, tmp,
                                        out, cs, css);   // h1 -> d_out
    k_mlp2<<<(N_NODESC + MT - 1) / MT, 256, 0, stream>>>(
        out, W2, b2, gamma, beta, cs, css, out);
}

// Round 12
// 231.524 us; speedup vs baseline: 1.1689x; 1.1689x over previous
//
#include <hip/hip_runtime.h>

#define N_NODESC 100000
#define N_EDGESC 1600000
#define BN_EPSC 1e-5f
#define NBUCK 1024              // coarse buckets (dst>>7, 128 nodes each), 782 used
#define NUSED 782               // ceil(100000/128)
#define SBLK 256                // castsort blocks
#define EPB (N_EDGESC / SBLK)   // 6250 edges per block
#define MT 128                  // nodes per MLP block
#define BCAP 4608               // LDS edge cap per bucket in aggf (mean 1562)
#define BCAPG 2304              // global per-bucket stride (mean 1562, ~18 sigma)

// ---------------------------------------------------------------------------
// K_castsort: ONE preprocessing kernel.
//  - bf16 cast of x (batched float4 loads for ILP)
//  - per-block LDS sort of its 6250 edges by coarse bucket
//  - one global atomicAdd(gcur[b], cnt) per (bucket, block) reserves a range
//    in bucket b's fixed region tmp[b*BCAPG ..]; flush coalesced runs.
// packed = src(17b) | attr<<17(2b) | (dst&127)<<19(7b).
// ---------------------------------------------------------------------------
__global__ __launch_bounds__(1024) void k_castsort(
    const int* __restrict__ ei, const int* __restrict__ ea,
    const float* __restrict__ x, uint2* __restrict__ xh4,
    int* __restrict__ gcur, int* __restrict__ tmp)
{
    __shared__ int ledge[EPB + 22];     // 6272 sorted packed edges
    __shared__ int cnt[NBUCK];
    __shared__ int cstart[NBUCK + 1];
    __shared__ int cur[NBUCK];
    __shared__ int gofs[NBUCK];
    __shared__ int wtot[16];
    const int t = threadIdx.x;
    const int k = blockIdx.x;

    cnt[t] = 0;
    {   // ---- bf16 cast, batched (registers released before edge phase) ----
        const float4* x4 = (const float4*)x;
        const int g = k * 1024 + t;
        float4 v[7];
        bool m[7];
        #pragma unroll
        for (int i = 0; i < 7; i++) {
            const int idx = g + i * (SBLK * 1024);
            m[i] = (idx < N_NODESC * 16);
            if (m[i]) v[i] = x4[idx];
        }
        #pragma unroll
        for (int i = 0; i < 7; i++) {
            if (m[i]) {
                const int idx = g + i * (SBLK * 1024);
                unsigned int a = __float_as_uint(v[i].x);
                unsigned int b = __float_as_uint(v[i].y);
                unsigned int c = __float_as_uint(v[i].z);
                unsigned int d = __float_as_uint(v[i].w);
                a = (a + 0x7FFFu + ((a >> 16) & 1u)) >> 16;
                b = (b + 0x7FFFu + ((b >> 16) & 1u)) >> 16;
                c = (c + 0x7FFFu + ((c >> 16) & 1u)) >> 16;
                d = (d + 0x7FFFu + ((d >> 16) & 1u)) >> 16;
                xh4[idx] = make_uint2(a | (b << 16), c | (d << 16));
            }
        }
    }
    __syncthreads();        // cnt zeroed before counting

    // ---- load edges + per-bucket count ---------------------------------
    int pk[7], bk[7];
    const int base = k * EPB;
    #pragma unroll
    for (int i = 0; i < 7; i++) {
        const int e = base + i * 1024 + t;
        if (e < base + EPB) {
            const int src = ei[e];
            const int dst = ei[N_EDGESC + e];
            const int a = ea[e];
            pk[i] = src | (a << 17) | ((dst & 127) << 19);
            bk[i] = dst >> 7;
            atomicAdd(&cnt[bk[i]], 1);
        } else bk[i] = -1;
    }
    __syncthreads();

    // ---- exclusive scan of 1024 counts (16-wave hierarchical) ----------
    {
        const int lane = t & 63;
        const int w = t >> 6;
        const int v = cnt[t];
        int inc = v;
        #pragma unroll
        for (int d = 1; d < 64; d <<= 1) {
            const int u = __shfl_up(inc, d);
            if (lane >= d) inc += u;
        }
        if (lane == 63) wtot[w] = inc;
        __syncthreads();
        int add = 0;
        #pragma unroll
        for (int w2 = 0; w2 < 16; w2++) if (w2 < w) add += wtot[w2];
        const int ex = inc - v + add;
        cstart[t] = ex;
        cur[t] = ex;
        if (t == 1023) cstart[NBUCK] = ex + v;
    }
    __syncthreads();

    // ---- place into LDS (bucket-major) + reserve global ranges ---------
    #pragma unroll
    for (int i = 0; i < 7; i++) {
        if (bk[i] >= 0) {
            const int pos = atomicAdd(&cur[bk[i]], 1);
            ledge[pos] = pk[i];
        }
    }
    {
        const int c = cnt[t];
        if (c > 0) gofs[t] = atomicAdd(&gcur[t], c);
    }
    __syncthreads();

    // ---- flush: binary search bucket, write coalesced runs -------------
    for (int i = t; i < EPB; i += 1024) {
        int lo = 0, hi = NBUCK;   // invariant: cstart[lo] <= i < cstart[hi]
        #pragma unroll
        for (int s = 0; s < 10; s++) {
            const int mid = (lo + hi) >> 1;
            if (cstart[mid] <= i) lo = mid; else hi = mid;
        }
        const int o = gofs[lo] + (i - cstart[lo]);
        if (o < BCAPG) tmp[lo * BCAPG + o] = ledge[i];
    }
}

// ---------------------------------------------------------------------------
// K_aggf: per-bucket node-sort (LDS) + register aggregation.  start/count
// come straight from the fixed-stride layout — no prefix scan anywhere.
// ---------------------------------------------------------------------------
__global__ __launch_bounds__(256) void k_aggf(
    const ushort* __restrict__ xh, const float* __restrict__ emb,
    const int* __restrict__ gcur, const int* __restrict__ tmp,
    float* __restrict__ agg)
{
    __shared__ int packedL[BCAP];
    __shared__ int cnt[128];
    __shared__ int cst[128];
    __shared__ int cur[128];
    const int t = threadIdx.x;
    const int b = blockIdx.x;
    const int start = b * BCAPG;
    int cntb = gcur[b];
    if (cntb > BCAPG) cntb = BCAPG;
    if (t < 128) cnt[t] = 0;
    __syncthreads();

    // pass 1: per-node counts
    for (int e = t; e < cntb; e += 256)
        atomicAdd(&cnt[(tmp[start + e] >> 19) & 127], 1);
    __syncthreads();
    if (t < 64) {   // scan 128 counts (two 64-lane halves)
        const int lane = t;
        const int v0 = cnt[lane];
        const int v1 = cnt[64 + lane];
        int i0 = v0, i1 = v1;
        #pragma unroll
        for (int d = 1; d < 64; d <<= 1) {
            const int u0 = __shfl_up(i0, d);
            const int u1 = __shfl_up(i1, d);
            if (lane >= d) { i0 += u0; i1 += u1; }
        }
        const int tot0 = __shfl(i0, 63);
        cst[lane] = i0 - v0;
        cst[64 + lane] = tot0 + i1 - v1;
        cur[lane] = i0 - v0;
        cur[64 + lane] = tot0 + i1 - v1;
    }
    __syncthreads();
    // pass 2: place node-sorted into LDS
    for (int e = t; e < cntb; e += 256) {
        const int p = tmp[start + e];
        const int pos = atomicAdd(&cur[(p >> 19) & 127], 1);
        if (pos < BCAP) packedL[pos] = p;
    }
    __syncthreads();

    // aggregate: group g -> nodes g*8 .. g*8+7, lane q = feature quarter
    const int g = t >> 4;
    const int q = t & 15;
    const ushort4* xv4 = (const ushort4*)xh;
    const float4* e4 = (const float4*)emb;
    float4* o4 = (float4*)agg;
    for (int j = 0; j < 8; j++) {
        const int nl = g * 8 + j;
        int e = cst[nl];
        const int ee = cur[nl];           // cur == end after pass 2
        float4 acc = make_float4(0.f, 0.f, 0.f, 0.f);
        for (; e + 2 <= ee; e += 2) {
            const int p0 = packedL[e];
            const int p1 = packedL[e + 1];
            const ushort4 u0 = xv4[(size_t)(p0 & 0x1FFFF) * 16 + q];
            const ushort4 u1 = xv4[(size_t)(p1 & 0x1FFFF) * 16 + q];
            const float4 t0 = e4[((p0 >> 17) & 3) * 16 + q];
            const float4 t1 = e4[((p1 >> 17) & 3) * 16 + q];
            acc.x += fmaxf(__uint_as_float((unsigned int)u0.x << 16) + t0.x, 0.f)
                   + fmaxf(__uint_as_float((unsigned int)u1.x << 16) + t1.x, 0.f);
            acc.y += fmaxf(__uint_as_float((unsigned int)u0.y << 16) + t0.y, 0.f)
                   + fmaxf(__uint_as_float((unsigned int)u1.y << 16) + t1.y, 0.f);
            acc.z += fmaxf(__uint_as_float((unsigned int)u0.z << 16) + t0.z, 0.f)
                   + fmaxf(__uint_as_float((unsigned int)u1.z << 16) + t1.z, 0.f);
            acc.w += fmaxf(__uint_as_float((unsigned int)u0.w << 16) + t0.w, 0.f)
                   + fmaxf(__uint_as_float((unsigned int)u1.w << 16) + t1.w, 0.f);
        }
        if (e < ee) {
            const int p0 = packedL[e];
            const ushort4 u0 = xv4[(size_t)(p0 & 0x1FFFF) * 16 + q];
            const float4 t0 = e4[((p0 >> 17) & 3) * 16 + q];
            acc.x += fmaxf(__uint_as_float((unsigned int)u0.x << 16) + t0.x, 0.f);
            acc.y += fmaxf(__uint_as_float((unsigned int)u0.y << 16) + t0.y, 0.f);
            acc.z += fmaxf(__uint_as_float((unsigned int)u0.z << 16) + t0.z, 0.f);
            acc.w += fmaxf(__uint_as_float((unsigned int)u0.w << 16) + t0.w, 0.f);
        }
        const int n = b * 128 + nl;
        if (n < N_NODESC) o4[(size_t)n * 16 + q] = acc;
    }
}

// ---------------------------------------------------------------------------
// K_mlp1: hbuf := ((1+eps)*x + hbuf) @ W1 + b1 ; BN column sums.
// 128 nodes/block, 4 nodes x 8 cols per thread, broadcast-friendly LDS.
// ---------------------------------------------------------------------------
__global__ __launch_bounds__(256) void k_mlp1(
    const float* __restrict__ x, float* hbuf,
    const float* __restrict__ W1, const float* __restrict__ b1,
    const float* __restrict__ epsp,
    float* __restrict__ cs, float* __restrict__ css)
{
    __shared__ float lin[MT][68];
    __shared__ float lW[4096];
    __shared__ float redS[4][64];
    __shared__ float redQ[4][64];
    const int t = threadIdx.x;
    const int nbase = blockIdx.x * MT;
    const float sc1 = 1.0f + epsp[0];

    {
        const float4* W4 = (const float4*)W1;
        float4* lW4 = (float4*)lW;
        #pragma unroll
        for (int i = 0; i < 4; i++) lW4[i * 256 + t] = W4[i * 256 + t];
    }
    {
        const float4* x4 = (const float4*)x;
        const float4* a4 = (const float4*)hbuf;
        #pragma unroll
        for (int i = 0; i < 8; i++) {
            const int fidx = i * 256 + t;
            const int row = fidx >> 4;
            const int q = fidx & 15;
            const int n = nbase + row;
            float4 v = make_float4(0.f, 0.f, 0.f, 0.f);
            if (n < N_NODESC) {
                const float4 xv = x4[(size_t)n * 16 + q];
                const float4 av = a4[(size_t)n * 16 + q];
                v.x = fmaf(sc1, xv.x, av.x);
                v.y = fmaf(sc1, xv.y, av.y);
                v.z = fmaf(sc1, xv.z, av.z);
                v.w = fmaf(sc1, xv.w, av.w);
            }
            *(float4*)&lin[row][q * 4] = v;
        }
    }
    __syncthreads();

    const int g = t & 7;
    const int r0 = t >> 3;
    const float4* lW4 = (const float4*)lW;
    const float4* b4 = (const float4*)b1;
    const float4 bb0 = b4[g * 2 + 0];
    const float4 bb1 = b4[g * 2 + 1];
    float4 a00 = bb0, a01 = bb1, a10 = bb0, a11 = bb1;
    float4 a20 = bb0, a21 = bb1, a30 = bb0, a31 = bb1;
    for (int k = 0; k < 64; k++) {
        const float v0 = lin[r0][k];
        const float v1 = lin[r0 + 32][k];
        const float v2 = lin[r0 + 64][k];
        const float v3 = lin[r0 + 96][k];
        const float4 w0 = lW4[k * 16 + g * 2 + 0];
        const float4 w1 = lW4[k * 16 + g * 2 + 1];
        a00.x = fmaf(v0, w0.x, a00.x); a00.y = fmaf(v0, w0.y, a00.y);
        a00.z = fmaf(v0, w0.z, a00.z); a00.w = fmaf(v0, w0.w, a00.w);
        a01.x = fmaf(v0, w1.x, a01.x); a01.y = fmaf(v0, w1.y, a01.y);
        a01.z = fmaf(v0, w1.z, a01.z); a01.w = fmaf(v0, w1.w, a01.w);
        a10.x = fmaf(v1, w0.x, a10.x); a10.y = fmaf(v1, w0.y, a10.y);
        a10.z = fmaf(v1, w0.z, a10.z); a10.w = fmaf(v1, w0.w, a10.w);
        a11.x = fmaf(v1, w1.x, a11.x); a11.y = fmaf(v1, w1.y, a11.y);
        a11.z = fmaf(v1, w1.z, a11.z); a11.w = fmaf(v1, w1.w, a11.w);
        a20.x = fmaf(v2, w0.x, a20.x); a20.y = fmaf(v2, w0.y, a20.y);
        a20.z = fmaf(v2, w0.z, a20.z); a20.w = fmaf(v2, w0.w, a20.w);
        a21.x = fmaf(v2, w1.x, a21.x); a21.y = fmaf(v2, w1.y, a21.y);
        a21.z = fmaf(v2, w1.z, a21.z); a21.w = fmaf(v2, w1.w, a21.w);
        a30.x = fmaf(v3, w0.x, a30.x); a30.y = fmaf(v3, w0.y, a30.y);
        a30.z = fmaf(v3, w0.z, a30.z); a30.w = fmaf(v3, w0.w, a30.w);
        a31.x = fmaf(v3, w1.x, a31.x); a31.y = fmaf(v3, w1.y, a31.y);
        a31.z = fmaf(v3, w1.z, a31.z); a31.w = fmaf(v3, w1.w, a31.w);
    }

    float4 A0[4] = {a00, a10, a20, a30};
    float4 A1[4] = {a01, a11, a21, a31};
    float4* h4 = (float4*)hbuf;
    float msk[4];
    #pragma unroll
    for (int j = 0; j < 4; j++) {
        const int n = nbase + r0 + 32 * j;
        msk[j] = (n < N_NODESC) ? 1.0f : 0.0f;
        if (n < N_NODESC) {
            h4[(size_t)n * 16 + g * 2 + 0] = A0[j];
            h4[(size_t)n * 16 + g * 2 + 1] = A1[j];
        }
    }

    float vs[8], vq[8];
    #pragma unroll
    for (int c = 0; c < 8; c++) { vs[c] = 0.f; vq[c] = 0.f; }
    #pragma unroll
    for (int j = 0; j < 4; j++) {
        const float e0[8] = {A0[j].x, A0[j].y, A0[j].z, A0[j].w,
                             A1[j].x, A1[j].y, A1[j].z, A1[j].w};
        #pragma unroll
        for (int c = 0; c < 8; c++) {
            const float v = e0[c] * msk[j];
            vs[c] += v;
            vq[c] += v * e0[c];
        }
    }
    #pragma unroll
    for (int o = 8; o < 64; o <<= 1) {
        #pragma unroll
        for (int c = 0; c < 8; c++) {
            vs[c] += __shfl_xor(vs[c], o);
            vq[c] += __shfl_xor(vq[c], o);
        }
    }
    const int lane = t & 63;
    const int w = t >> 6;
    if (lane < 8) {
        #pragma unroll
        for (int c = 0; c < 8; c++) {
            redS[w][lane * 8 + c] = vs[c];
            redQ[w][lane * 8 + c] = vq[c];
        }
    }
    __syncthreads();
    if (t < 64) {
        const float s = redS[0][t] + redS[1][t] + redS[2][t] + redS[3][t];
        const float qq = redQ[0][t] + redQ[1][t] + redQ[2][t] + redQ[3][t];
        unsafeAtomicAdd(&cs[t], s);
        unsafeAtomicAdd(&css[t], qq);
    }
}

// ---------------------------------------------------------------------------
// K_mlp2: out = relu(BN(h1)) @ W2 + b2.  h1 aliases out; LDS-staged.
// ---------------------------------------------------------------------------
__global__ __launch_bounds__(256) void k_mlp2(
    const float* h1, const float* __restrict__ W2, const float* __restrict__ b2,
    const float* __restrict__ gamma, const float* __restrict__ beta,
    const float* __restrict__ cs, const float* __restrict__ css,
    float* out)
{
    __shared__ float lin[MT][68];
    __shared__ float lW[4096];
    __shared__ float scl[64];
    __shared__ float sft[64];
    const int t = threadIdx.x;
    const int nbase = blockIdx.x * MT;

    if (t < 64) {
        const float inv = 1.0f / (float)N_NODESC;
        const float mu = cs[t] * inv;
        const float var = css[t] * inv - mu * mu;
        const float rs = rsqrtf(var + BN_EPSC);
        const float s = rs * gamma[t];
        scl[t] = s;
        sft[t] = fmaf(-mu, s, beta[t]);
    }
    {
        const float4* W4 = (const float4*)W2;
        float4* lW4 = (float4*)lW;
        #pragma unroll
        for (int i = 0; i < 4; i++) lW4[i * 256 + t] = W4[i * 256 + t];
    }
    __syncthreads();
    {
        const float4* h4 = (const float4*)h1;
        #pragma unroll
        for (int i = 0; i < 8; i++) {
            const int fidx = i * 256 + t;
            const int row = fidx >> 4;
            const int q = fidx & 15;
            const int n = nbase + row;
            float4 v = make_float4(0.f, 0.f, 0.f, 0.f);
            if (n < N_NODESC) {
                const float4 h = h4[(size_t)n * 16 + q];
                const int c = q * 4;
                v.x = fmaxf(fmaf(h.x, scl[c + 0], sft[c + 0]), 0.f);
                v.y = fmaxf(fmaf(h.y, scl[c + 1], sft[c + 1]), 0.f);
                v.z = fmaxf(fmaf(h.z, scl[c + 2], sft[c + 2]), 0.f);
                v.w = fmaxf(fmaf(h.w, scl[c + 3], sft[c + 3]), 0.f);
            }
            *(float4*)&lin[row][q * 4] = v;
        }
    }
    __syncthreads();

    const int g = t & 7;
    const int r0 = t >> 3;
    const float4* lW4 = (const float4*)lW;
    const float4* b4 = (const float4*)b2;
    const float4 bb0 = b4[g * 2 + 0];
    const float4 bb1 = b4[g * 2 + 1];
    float4 a00 = bb0, a01 = bb1, a10 = bb0, a11 = bb1;
    float4 a20 = bb0, a21 = bb1, a30 = bb0, a31 = bb1;
    for (int k = 0; k < 64; k++) {
        const float v0 = lin[r0][k];
        const float v1 = lin[r0 + 32][k];
        const float v2 = lin[r0 + 64][k];
        const float v3 = lin[r0 + 96][k];
        const float4 w0 = lW4[k * 16 + g * 2 + 0];
        const float4 w1 = lW4[k * 16 + g * 2 + 1];
        a00.x = fmaf(v0, w0.x, a00.x); a00.y = fmaf(v0, w0.y, a00.y);
        a00.z = fmaf(v0, w0.z, a00.z); a00.w = fmaf(v0, w0.w, a00.w);
        a01.x = fmaf(v0, w1.x, a01.x); a01.y = fmaf(v0, w1.y, a01.y);
        a01.z = fmaf(v0, w1.z, a01.z); a01.w = fmaf(v0, w1.w, a01.w);
        a10.x = fmaf(v1, w0.x, a10.x); a10.y = fmaf(v1, w0.y, a10.y);
        a10.z = fmaf(v1, w0.z, a10.z); a10.w = fmaf(v1, w0.w, a10.w);
        a11.x = fmaf(v1, w1.x, a11.x); a11.y = fmaf(v1, w1.y, a11.y);
        a11.z = fmaf(v1, w1.z, a11.z); a11.w = fmaf(v1, w1.w, a11.w);
        a20.x = fmaf(v2, w0.x, a20.x); a20.y = fmaf(v2, w0.y, a20.y);
        a20.z = fmaf(v2, w0.z, a20.z); a20.w = fmaf(v2, w0.w, a20.w);
        a21.x = fmaf(v2, w1.x, a21.x); a21.y = fmaf(v2, w1.y, a21.y);
        a21.z = fmaf(v2, w1.z, a21.z); a21.w = fmaf(v2, w1.w, a21.w);
        a30.x = fmaf(v3, w0.x, a30.x); a30.y = fmaf(v3, w0.y, a30.y);
        a30.z = fmaf(v3, w0.z, a30.z); a30.w = fmaf(v3, w0.w, a30.w);
        a31.x = fmaf(v3, w1.x, a31.x); a31.y = fmaf(v3, w1.y, a31.y);
        a31.z = fmaf(v3, w1.z, a31.z); a31.w = fmaf(v3, w1.w, a31.w);
    }
    const float4 A0[4] = {a00, a10, a20, a30};
    const float4 A1[4] = {a01, a11, a21, a31};
    float4* o4 = (float4*)out;
    #pragma unroll
    for (int j = 0; j < 4; j++) {
        const int n = nbase + r0 + 32 * j;
        if (n < N_NODESC) {
            o4[(size_t)n * 16 + g * 2 + 0] = A0[j];
            o4[(size_t)n * 16 + g * 2 + 1] = A1[j];
        }
    }
}

// ---------------------------------------------------------------------------
extern "C" void kernel_launch(void* const* d_in, const int* in_sizes, int n_in,
                              void* d_out, int out_size, void* d_ws, size_t ws_size,
                              hipStream_t stream) {
    const float* x     = (const float*)d_in[0];
    const float* emb   = (const float*)d_in[1];
    const float* eps   = (const float*)d_in[2];
    const float* W1    = (const float*)d_in[3];
    const float* b1    = (const float*)d_in[4];
    const float* gamma = (const float*)d_in[5];
    const float* beta  = (const float*)d_in[6];
    const float* W2    = (const float*)d_in[7];
    const float* b2    = (const float*)d_in[8];
    const int*   ei    = (const int*)d_in[9];
    const int*   ea    = (const int*)d_in[10];
    float* out = (float*)d_out;

    // ws: [cs 64][css 64][gcur NBUCK][tmp NBUCK*BCAPG][xh N*64 bf16]  (~22 MB)
    float* ws    = (float*)d_ws;
    float* cs    = ws;
    float* css   = ws + 64;
    int*   gcur  = (int*)(ws + 128);
    int*   tmp   = gcur + NBUCK;
    ushort* xh   = (ushort*)(tmp + (size_t)NBUCK * BCAPG);

    // zero cs/css/gcur (4.6 KB)
    hipMemsetAsync(d_ws, 0, (size_t)(128 + NBUCK) * sizeof(int), stream);

    k_castsort<<<SBLK, 1024, 0, stream>>>(ei, ea, x, (uint2*)xh, gcur, tmp);
    k_aggf<<<NUSED, 256, 0, stream>>>(xh, emb, gcur, tmp, out);       // agg -> d_out
    k_mlp1<<<NUSED, 256, 0, stream>>>(x, out, W1, b1, eps, cs, css);  // h1 -> d_out
    k_mlp2<<<NUSED, 256, 0, stream>>>(out, W2, b2, gamma, beta, cs, css, out);
}

// Round 13
// 227.825 us; speedup vs baseline: 1.1879x; 1.0162x over previous
//
#include <hip/hip_runtime.h>

#define N_NODESC 100000
#define N_EDGESC 1600000
#define BN_EPSC 1e-5f
#define NBUCK 1024              // coarse buckets (dst>>7, 128 nodes each), 782 used
#define NUSED 782               // ceil(100000/128)
#define SBLK 256                // castsort blocks
#define EPB (N_EDGESC / SBLK)   // 6250 edges per block
#define MT 128                  // nodes per MLP block
#define BCAP 4608               // LDS edge cap per bucket in aggf (mean 1562)
#define BCAPG 2304              // global per-bucket stride (mean 1562, ~18 sigma)

// ---------------------------------------------------------------------------
// K_castsort: ONE preprocessing kernel.
//  - bf16 cast of x (batched float4 loads for ILP)
//  - per-block LDS sort of its 6250 edges by coarse bucket
//  - one global atomicAdd(gcur[b], cnt) per (bucket, block) reserves a range
//    in bucket b's fixed region tmp[b*BCAPG ..]; flush coalesced runs.
// packed = src(17b) | attr<<17(2b) | (dst&127)<<19(7b).
// ---------------------------------------------------------------------------
__global__ __launch_bounds__(1024) void k_castsort(
    const int* __restrict__ ei, const int* __restrict__ ea,
    const float* __restrict__ x, uint2* __restrict__ xh4,
    int* __restrict__ gcur, int* __restrict__ tmp)
{
    __shared__ int ledge[EPB + 22];     // 6272 sorted packed edges
    __shared__ int cnt[NBUCK];
    __shared__ int cstart[NBUCK + 1];
    __shared__ int cur[NBUCK];
    __shared__ int gofs[NBUCK];
    __shared__ int wtot[16];
    const int t = threadIdx.x;
    const int k = blockIdx.x;

    cnt[t] = 0;
    {   // ---- bf16 cast, batched ----
        const float4* x4 = (const float4*)x;
        const int g = k * 1024 + t;
        float4 v[7];
        bool m[7];
        #pragma unroll
        for (int i = 0; i < 7; i++) {
            const int idx = g + i * (SBLK * 1024);
            m[i] = (idx < N_NODESC * 16);
            if (m[i]) v[i] = x4[idx];
        }
        #pragma unroll
        for (int i = 0; i < 7; i++) {
            if (m[i]) {
                const int idx = g + i * (SBLK * 1024);
                unsigned int a = __float_as_uint(v[i].x);
                unsigned int b = __float_as_uint(v[i].y);
                unsigned int c = __float_as_uint(v[i].z);
                unsigned int d = __float_as_uint(v[i].w);
                a = (a + 0x7FFFu + ((a >> 16) & 1u)) >> 16;
                b = (b + 0x7FFFu + ((b >> 16) & 1u)) >> 16;
                c = (c + 0x7FFFu + ((c >> 16) & 1u)) >> 16;
                d = (d + 0x7FFFu + ((d >> 16) & 1u)) >> 16;
                xh4[idx] = make_uint2(a | (b << 16), c | (d << 16));
            }
        }
    }
    __syncthreads();        // cnt zeroed before counting

    // ---- load edges + per-bucket count ---------------------------------
    int pk[7], bk[7];
    const int base = k * EPB;
    #pragma unroll
    for (int i = 0; i < 7; i++) {
        const int e = base + i * 1024 + t;
        if (e < base + EPB) {
            const int src = ei[e];
            const int dst = ei[N_EDGESC + e];
            const int a = ea[e];
            pk[i] = src | (a << 17) | ((dst & 127) << 19);
            bk[i] = dst >> 7;
            atomicAdd(&cnt[bk[i]], 1);
        } else bk[i] = -1;
    }
    __syncthreads();

    // ---- exclusive scan of 1024 counts (16-wave hierarchical) ----------
    {
        const int lane = t & 63;
        const int w = t >> 6;
        const int v = cnt[t];
        int inc = v;
        #pragma unroll
        for (int d = 1; d < 64; d <<= 1) {
            const int u = __shfl_up(inc, d);
            if (lane >= d) inc += u;
        }
        if (lane == 63) wtot[w] = inc;
        __syncthreads();
        int add = 0;
        #pragma unroll
        for (int w2 = 0; w2 < 16; w2++) if (w2 < w) add += wtot[w2];
        const int ex = inc - v + add;
        cstart[t] = ex;
        cur[t] = ex;
        if (t == 1023) cstart[NBUCK] = ex + v;
    }
    __syncthreads();

    // ---- place into LDS (bucket-major) + reserve global ranges ---------
    #pragma unroll
    for (int i = 0; i < 7; i++) {
        if (bk[i] >= 0) {
            const int pos = atomicAdd(&cur[bk[i]], 1);
            ledge[pos] = pk[i];
        }
    }
    {
        const int c = cnt[t];
        if (c > 0) gofs[t] = atomicAdd(&gcur[t], c);
    }
    __syncthreads();

    // ---- flush: binary search bucket, write coalesced runs -------------
    for (int i = t; i < EPB; i += 1024) {
        int lo = 0, hi = NBUCK;   // invariant: cstart[lo] <= i < cstart[hi]
        #pragma unroll
        for (int s = 0; s < 10; s++) {
            const int mid = (lo + hi) >> 1;
            if (cstart[mid] <= i) lo = mid; else hi = mid;
        }
        const int o = gofs[lo] + (i - cstart[lo]);
        if (o < BCAPG) tmp[lo * BCAPG + o] = ledge[i];
    }
}

// ---------------------------------------------------------------------------
// K_aggf: per-bucket node-sort (LDS) + register aggregation with self-term
// init acc = (1+eps)*x[n] (f32, coalesced — hides under gather latency).
// Unroll-4 inner loop: 4 independent row-gathers in flight per group.
// ---------------------------------------------------------------------------
__global__ __launch_bounds__(256) void k_aggf(
    const ushort* __restrict__ xh, const float* __restrict__ emb,
    const float* __restrict__ x, const float* __restrict__ epsp,
    const int* __restrict__ gcur, const int* __restrict__ tmp,
    float* __restrict__ agg)
{
    __shared__ int packedL[BCAP];
    __shared__ int cnt[128];
    __shared__ int cst[128];
    __shared__ int cur[128];
    const int t = threadIdx.x;
    const int b = blockIdx.x;
    const int start = b * BCAPG;
    int cntb = gcur[b];
    if (cntb > BCAPG) cntb = BCAPG;
    if (t < 128) cnt[t] = 0;
    __syncthreads();

    // pass 1: per-node counts
    for (int e = t; e < cntb; e += 256)
        atomicAdd(&cnt[(tmp[start + e] >> 19) & 127], 1);
    __syncthreads();
    if (t < 64) {   // scan 128 counts (two 64-lane halves)
        const int lane = t;
        const int v0 = cnt[lane];
        const int v1 = cnt[64 + lane];
        int i0 = v0, i1 = v1;
        #pragma unroll
        for (int d = 1; d < 64; d <<= 1) {
            const int u0 = __shfl_up(i0, d);
            const int u1 = __shfl_up(i1, d);
            if (lane >= d) { i0 += u0; i1 += u1; }
        }
        const int tot0 = __shfl(i0, 63);
        cst[lane] = i0 - v0;
        cst[64 + lane] = tot0 + i1 - v1;
        cur[lane] = i0 - v0;
        cur[64 + lane] = tot0 + i1 - v1;
    }
    __syncthreads();
    // pass 2: place node-sorted into LDS
    for (int e = t; e < cntb; e += 256) {
        const int p = tmp[start + e];
        const int pos = atomicAdd(&cur[(p >> 19) & 127], 1);
        if (pos < BCAP) packedL[pos] = p;
    }
    __syncthreads();

    // aggregate: group g -> nodes g*8 .. g*8+7, lane q = feature quarter
    const int g = t >> 4;
    const int q = t & 15;
    const float sc1 = 1.0f + epsp[0];
    const ushort4* xv4 = (const ushort4*)xh;
    const float4* x4 = (const float4*)x;
    const float4* e4 = (const float4*)emb;
    float4* o4 = (float4*)agg;
    for (int j = 0; j < 8; j++) {
        const int nl = g * 8 + j;
        const int n = b * 128 + nl;
        int e = cst[nl];
        const int ee = cur[nl];           // cur == end after pass 2
        float4 acc = make_float4(0.f, 0.f, 0.f, 0.f);
        if (n < N_NODESC) {
            const float4 xv = x4[(size_t)n * 16 + q];
            acc.x = sc1 * xv.x; acc.y = sc1 * xv.y;
            acc.z = sc1 * xv.z; acc.w = sc1 * xv.w;
        }
        for (; e + 4 <= ee; e += 4) {
            const int p0 = packedL[e];
            const int p1 = packedL[e + 1];
            const int p2 = packedL[e + 2];
            const int p3 = packedL[e + 3];
            const ushort4 u0 = xv4[(size_t)(p0 & 0x1FFFF) * 16 + q];
            const ushort4 u1 = xv4[(size_t)(p1 & 0x1FFFF) * 16 + q];
            const ushort4 u2 = xv4[(size_t)(p2 & 0x1FFFF) * 16 + q];
            const ushort4 u3 = xv4[(size_t)(p3 & 0x1FFFF) * 16 + q];
            const float4 t0 = e4[((p0 >> 17) & 3) * 16 + q];
            const float4 t1 = e4[((p1 >> 17) & 3) * 16 + q];
            const float4 t2 = e4[((p2 >> 17) & 3) * 16 + q];
            const float4 t3 = e4[((p3 >> 17) & 3) * 16 + q];
            acc.x += fmaxf(__uint_as_float((unsigned int)u0.x << 16) + t0.x, 0.f)
                   + fmaxf(__uint_as_float((unsigned int)u1.x << 16) + t1.x, 0.f)
                   + fmaxf(__uint_as_float((unsigned int)u2.x << 16) + t2.x, 0.f)
                   + fmaxf(__uint_as_float((unsigned int)u3.x << 16) + t3.x, 0.f);
            acc.y += fmaxf(__uint_as_float((unsigned int)u0.y << 16) + t0.y, 0.f)
                   + fmaxf(__uint_as_float((unsigned int)u1.y << 16) + t1.y, 0.f)
                   + fmaxf(__uint_as_float((unsigned int)u2.y << 16) + t2.y, 0.f)
                   + fmaxf(__uint_as_float((unsigned int)u3.y << 16) + t3.y, 0.f);
            acc.z += fmaxf(__uint_as_float((unsigned int)u0.z << 16) + t0.z, 0.f)
                   + fmaxf(__uint_as_float((unsigned int)u1.z << 16) + t1.z, 0.f)
                   + fmaxf(__uint_as_float((unsigned int)u2.z << 16) + t2.z, 0.f)
                   + fmaxf(__uint_as_float((unsigned int)u3.z << 16) + t3.z, 0.f);
            acc.w += fmaxf(__uint_as_float((unsigned int)u0.w << 16) + t0.w, 0.f)
                   + fmaxf(__uint_as_float((unsigned int)u1.w << 16) + t1.w, 0.f)
                   + fmaxf(__uint_as_float((unsigned int)u2.w << 16) + t2.w, 0.f)
                   + fmaxf(__uint_as_float((unsigned int)u3.w << 16) + t3.w, 0.f);
        }
        for (; e < ee; e++) {
            const int p0 = packedL[e];
            const ushort4 u0 = xv4[(size_t)(p0 & 0x1FFFF) * 16 + q];
            const float4 t0 = e4[((p0 >> 17) & 3) * 16 + q];
            acc.x += fmaxf(__uint_as_float((unsigned int)u0.x << 16) + t0.x, 0.f);
            acc.y += fmaxf(__uint_as_float((unsigned int)u0.y << 16) + t0.y, 0.f);
            acc.z += fmaxf(__uint_as_float((unsigned int)u0.z << 16) + t0.z, 0.f);
            acc.w += fmaxf(__uint_as_float((unsigned int)u0.w << 16) + t0.w, 0.f);
        }
        if (n < N_NODESC) o4[(size_t)n * 16 + q] = acc;
    }
}

// ---------------------------------------------------------------------------
// K_mlp1: hbuf := hbuf @ W1 + b1 ; BN column sums.  (self-term already in
// hbuf from aggf.)  128 nodes/block, 4 nodes x 8 cols per thread.
// ---------------------------------------------------------------------------
__global__ __launch_bounds__(256) void k_mlp1(
    float* hbuf,
    const float* __restrict__ W1, const float* __restrict__ b1,
    float* __restrict__ cs, float* __restrict__ css)
{
    __shared__ float lin[MT][68];
    __shared__ float lW[4096];
    __shared__ float redS[4][64];
    __shared__ float redQ[4][64];
    const int t = threadIdx.x;
    const int nbase = blockIdx.x * MT;

    {
        const float4* W4 = (const float4*)W1;
        float4* lW4 = (float4*)lW;
        #pragma unroll
        for (int i = 0; i < 4; i++) lW4[i * 256 + t] = W4[i * 256 + t];
    }
    {
        const float4* a4 = (const float4*)hbuf;
        #pragma unroll
        for (int i = 0; i < 8; i++) {
            const int fidx = i * 256 + t;
            const int row = fidx >> 4;
            const int q = fidx & 15;
            const int n = nbase + row;
            float4 v = make_float4(0.f, 0.f, 0.f, 0.f);
            if (n < N_NODESC) v = a4[(size_t)n * 16 + q];
            *(float4*)&lin[row][q * 4] = v;
        }
    }
    __syncthreads();

    const int g = t & 7;
    const int r0 = t >> 3;
    const float4* lW4 = (const float4*)lW;
    const float4* b4 = (const float4*)b1;
    const float4 bb0 = b4[g * 2 + 0];
    const float4 bb1 = b4[g * 2 + 1];
    float4 a00 = bb0, a01 = bb1, a10 = bb0, a11 = bb1;
    float4 a20 = bb0, a21 = bb1, a30 = bb0, a31 = bb1;
    for (int k = 0; k < 64; k++) {
        const float v0 = lin[r0][k];
        const float v1 = lin[r0 + 32][k];
        const float v2 = lin[r0 + 64][k];
        const float v3 = lin[r0 + 96][k];
        const float4 w0 = lW4[k * 16 + g * 2 + 0];
        const float4 w1 = lW4[k * 16 + g * 2 + 1];
        a00.x = fmaf(v0, w0.x, a00.x); a00.y = fmaf(v0, w0.y, a00.y);
        a00.z = fmaf(v0, w0.z, a00.z); a00.w = fmaf(v0, w0.w, a00.w);
        a01.x = fmaf(v0, w1.x, a01.x); a01.y = fmaf(v0, w1.y, a01.y);
        a01.z = fmaf(v0, w1.z, a01.z); a01.w = fmaf(v0, w1.w, a01.w);
        a10.x = fmaf(v1, w0.x, a10.x); a10.y = fmaf(v1, w0.y, a10.y);
        a10.z = fmaf(v1, w0.z, a10.z); a10.w = fmaf(v1, w0.w, a10.w);
        a11.x = fmaf(v1, w1.x, a11.x); a11.y = fmaf(v1, w1.y, a11.y);
        a11.z = fmaf(v1, w1.z, a11.z); a11.w = fmaf(v1, w1.w, a11.w);
        a20.x = fmaf(v2, w0.x, a20.x); a20.y = fmaf(v2, w0.y, a20.y);
        a20.z = fmaf(v2, w0.z, a20.z); a20.w = fmaf(v2, w0.w, a20.w);
        a21.x = fmaf(v2, w1.x, a21.x); a21.y = fmaf(v2, w1.y, a21.y);
        a21.z = fmaf(v2, w1.z, a21.z); a21.w = fmaf(v2, w1.w, a21.w);
        a30.x = fmaf(v3, w0.x, a30.x); a30.y = fmaf(v3, w0.y, a30.y);
        a30.z = fmaf(v3, w0.z, a30.z); a30.w = fmaf(v3, w0.w, a30.w);
        a31.x = fmaf(v3, w1.x, a31.x); a31.y = fmaf(v3, w1.y, a31.y);
        a31.z = fmaf(v3, w1.z, a31.z); a31.w = fmaf(v3, w1.w, a31.w);
    }

    float4 A0[4] = {a00, a10, a20, a30};
    float4 A1[4] = {a01, a11, a21, a31};
    float4* h4 = (float4*)hbuf;
    float msk[4];
    #pragma unroll
    for (int j = 0; j < 4; j++) {
        const int n = nbase + r0 + 32 * j;
        msk[j] = (n < N_NODESC) ? 1.0f : 0.0f;
        if (n < N_NODESC) {
            h4[(size_t)n * 16 + g * 2 + 0] = A0[j];
            h4[(size_t)n * 16 + g * 2 + 1] = A1[j];
        }
    }

    float vs[8], vq[8];
    #pragma unroll
    for (int c = 0; c < 8; c++) { vs[c] = 0.f; vq[c] = 0.f; }
    #pragma unroll
    for (int j = 0; j < 4; j++) {
        const float e0[8] = {A0[j].x, A0[j].y, A0[j].z, A0[j].w,
                             A1[j].x, A1[j].y, A1[j].z, A1[j].w};
        #pragma unroll
        for (int c = 0; c < 8; c++) {
            const float v = e0[c] * msk[j];
            vs[c] += v;
            vq[c] += v * e0[c];
        }
    }
    #pragma unroll
    for (int o = 8; o < 64; o <<= 1) {
        #pragma unroll
        for (int c = 0; c < 8; c++) {
            vs[c] += __shfl_xor(vs[c], o);
            vq[c] += __shfl_xor(vq[c], o);
        }
    }
    const int lane = t & 63;
    const int w = t >> 6;
    if (lane < 8) {
        #pragma unroll
        for (int c = 0; c < 8; c++) {
            redS[w][lane * 8 + c] = vs[c];
            redQ[w][lane * 8 + c] = vq[c];
        }
    }
    __syncthreads();
    if (t < 64) {
        const float s = redS[0][t] + redS[1][t] + redS[2][t] + redS[3][t];
        const float qq = redQ[0][t] + redQ[1][t] + redQ[2][t] + redQ[3][t];
        unsafeAtomicAdd(&cs[t], s);
        unsafeAtomicAdd(&css[t], qq);
    }
}

// ---------------------------------------------------------------------------
// K_mlp2: out = relu(BN(h1)) @ W2 + b2.  h1 aliases out; LDS-staged.
// ---------------------------------------------------------------------------
__global__ __launch_bounds__(256) void k_mlp2(
    const float* h1, const float* __restrict__ W2, const float* __restrict__ b2,
    const float* __restrict__ gamma, const float* __restrict__ beta,
    const float* __restrict__ cs, const float* __restrict__ css,
    float* out)
{
    __shared__ float lin[MT][68];
    __shared__ float lW[4096];
    __shared__ float scl[64];
    __shared__ float sft[64];
    const int t = threadIdx.x;
    const int nbase = blockIdx.x * MT;

    if (t < 64) {
        const float inv = 1.0f / (float)N_NODESC;
        const float mu = cs[t] * inv;
        const float var = css[t] * inv - mu * mu;
        const float rs = rsqrtf(var + BN_EPSC);
        const float s = rs * gamma[t];
        scl[t] = s;
        sft[t] = fmaf(-mu, s, beta[t]);
    }
    {
        const float4* W4 = (const float4*)W2;
        float4* lW4 = (float4*)lW;
        #pragma unroll
        for (int i = 0; i < 4; i++) lW4[i * 256 + t] = W4[i * 256 + t];
    }
    __syncthreads();
    {
        const float4* h4 = (const float4*)h1;
        #pragma unroll
        for (int i = 0; i < 8; i++) {
            const int fidx = i * 256 + t;
            const int row = fidx >> 4;
            const int q = fidx & 15;
            const int n = nbase + row;
            float4 v = make_float4(0.f, 0.f, 0.f, 0.f);
            if (n < N_NODESC) {
                const float4 h = h4[(size_t)n * 16 + q];
                const int c = q * 4;
                v.x = fmaxf(fmaf(h.x, scl[c + 0], sft[c + 0]), 0.f);
                v.y = fmaxf(fmaf(h.y, scl[c + 1], sft[c + 1]), 0.f);
                v.z = fmaxf(fmaf(h.z, scl[c + 2], sft[c + 2]), 0.f);
                v.w = fmaxf(fmaf(h.w, scl[c + 3], sft[c + 3]), 0.f);
            }
            *(float4*)&lin[row][q * 4] = v;
        }
    }
    __syncthreads();

    const int g = t & 7;
    const int r0 = t >> 3;
    const float4* lW4 = (const float4*)lW;
    const float4* b4 = (const float4*)b2;
    const float4 bb0 = b4[g * 2 + 0];
    const float4 bb1 = b4[g * 2 + 1];
    float4 a00 = bb0, a01 = bb1, a10 = bb0, a11 = bb1;
    float4 a20 = bb0, a21 = bb1, a30 = bb0, a31 = bb1;
    for (int k = 0; k < 64; k++) {
        const float v0 = lin[r0][k];
        const float v1 = lin[r0 + 32][k];
        const float v2 = lin[r0 + 64][k];
        const float v3 = lin[r0 + 96][k];
        const float4 w0 = lW4[k * 16 + g * 2 + 0];
        const float4 w1 = lW4[k * 16 + g * 2 + 1];
        a00.x = fmaf(v0, w0.x, a00.x); a00.y = fmaf(v0, w0.y, a00.y);
        a00.z = fmaf(v0, w0.z, a00.z); a00.w = fmaf(v0, w0.w, a00.w);
        a01.x = fmaf(v0, w1.x, a01.x); a01.y = fmaf(v0, w1.y, a01.y);
        a01.z = fmaf(v0, w1.z, a01.z); a01.w = fmaf(v0, w1.w, a01.w);
        a10.x = fmaf(v1, w0.x, a10.x); a10.y = fmaf(v1, w0.y, a10.y);
        a10.z = fmaf(v1, w0.z, a10.z); a10.w = fmaf(v1, w0.w, a10.w);
        a11.x = fmaf(v1, w1.x, a11.x); a11.y = fmaf(v1, w1.y, a11.y);
        a11.z = fmaf(v1, w1.z, a11.z); a11.w = fmaf(v1, w1.w, a11.w);
        a20.x = fmaf(v2, w0.x, a20.x); a20.y = fmaf(v2, w0.y, a20.y);
        a20.z = fmaf(v2, w0.z, a20.z); a20.w = fmaf(v2, w0.w, a20.w);
        a21.x = fmaf(v2, w1.x, a21.x); a21.y = fmaf(v2, w1.y, a21.y);
        a21.z = fmaf(v2, w1.z, a21.z); a21.w = fmaf(v2, w1.w, a21.w);
        a30.x = fmaf(v3, w0.x, a30.x); a30.y = fmaf(v3, w0.y, a30.y);
        a30.z = fmaf(v3, w0.z, a30.z); a30.w = fmaf(v3, w0.w, a30.w);
        a31.x = fmaf(v3, w1.x, a31.x); a31.y = fmaf(v3, w1.y, a31.y);
        a31.z = fmaf(v3, w1.z, a31.z); a31.w = fmaf(v3, w1.w, a31.w);
    }
    const float4 A0[4] = {a00, a10, a20, a30};
    const float4 A1[4] = {a01, a11, a21, a31};
    float4* o4 = (float4*)out;
    #pragma unroll
    for (int j = 0; j < 4; j++) {
        const int n = nbase + r0 + 32 * j;
        if (n < N_NODESC) {
            o4[(size_t)n * 16 + g * 2 + 0] = A0[j];
            o4[(size_t)n * 16 + g * 2 + 1] = A1[j];
        }
    }
}

// ---------------------------------------------------------------------------
extern "C" void kernel_launch(void* const* d_in, const int* in_sizes, int n_in,
                              void* d_out, int out_size, void* d_ws, size_t ws_size,
                              hipStream_t stream) {
    const float* x     = (const float*)d_in[0];
    const float* emb   = (const float*)d_in[1];
    const float* eps   = (const float*)d_in[2];
    const float* W1    = (const float*)d_in[3];
    const float* b1    = (const float*)d_in[4];
    const float* gamma = (const float*)d_in[5];
    const float* beta  = (const float*)d_in[6];
    const float* W2    = (const float*)d_in[7];
    const float* b2    = (const float*)d_in[8];
    const int*   ei    = (const int*)d_in[9];
    const int*   ea    = (const int*)d_in[10];
    float* out = (float*)d_out;

    // ws: [cs 64][css 64][gcur NBUCK][tmp NBUCK*BCAPG][xh N*64 bf16]  (~22 MB)
    float* ws    = (float*)d_ws;
    float* cs    = ws;
    float* css   = ws + 64;
    int*   gcur  = (int*)(ws + 128);
    int*   tmp   = gcur + NBUCK;
    ushort* xh   = (ushort*)(tmp + (size_t)NBUCK * BCAPG);

    // zero cs/css/gcur (4.6 KB)
    hipMemsetAsync(d_ws, 0, (size_t)(128 + NBUCK) * sizeof(int), stream);

    k_castsort<<<SBLK, 1024, 0, stream>>>(ei, ea, x, (uint2*)xh, gcur, tmp);
    k_aggf<<<NUSED, 256, 0, stream>>>(xh, emb, x, eps, gcur, tmp, out);  // (1+eps)x+agg -> d_out
    k_mlp1<<<NUSED, 256, 0, stream>>>(out, W1, b1, cs, css);             // h1 -> d_out
    k_mlp2<<<NUSED, 256, 0, stream>>>(out, W2, b2, gamma, beta, cs, css, out);
}